// Round 4
// baseline (818.718 us; speedup 1.0000x reference)
//
#include <hip/hip_runtime.h>
#include <cstdint>
#include <cstddef>

// ---------------------------------------------------------------------------
// BitMoE FFN (top-2 of 8 experts), MI355X/gfx950.  Round 4.
// GEMMs: int8 MFMA, fragment-packed operands, M=128 register tiles
// (8 accs/wave in gu, 4 in down) for 87 MAC/L2-byte; A shared via L1.
// Weight pipeline: per-tensor wabs -> scales(+exact compare thr) -> pack
// (LDS transpose), tensor L3-resident between passes.
// ---------------------------------------------------------------------------

#define T_TOK 2048
#define HDIM  1024
#define FDIM  4096
#define NEXP  8
#define FH    (FDIM * HDIM)     // 2^22
#define KTOP  2253              // ceil(0.55 * 4096)
#define EPSF  1e-8f
#define PPAD  5120              // 4096 pairs + per-expert 128-alignment pad

typedef int v4i  __attribute__((ext_vector_type(4)));
typedef int v16i __attribute__((ext_vector_type(16)));

// ---------------- pass 1: per-matrix mean|w| partials ----------------------
__global__ __launch_bounds__(256) void k_wabs(const float* __restrict__ w,
                                              float* __restrict__ partials) {
  int m = blockIdx.x, blk = blockIdx.y, tid = threadIdx.x;
  const float4* p = (const float4*)(w + (size_t)m * FH + (size_t)blk * 32768) + tid;
  float s0 = 0.f, s1 = 0.f, s2 = 0.f, s3 = 0.f;
#pragma unroll
  for (int i = 0; i < 8; i++) {
    float4 a = p[(4 * i + 0) * 256];
    float4 b = p[(4 * i + 1) * 256];
    float4 c = p[(4 * i + 2) * 256];
    float4 d = p[(4 * i + 3) * 256];
    s0 += fabsf(a.x) + fabsf(a.y) + fabsf(a.z) + fabsf(a.w);
    s1 += fabsf(b.x) + fabsf(b.y) + fabsf(b.z) + fabsf(b.w);
    s2 += fabsf(c.x) + fabsf(c.y) + fabsf(c.z) + fabsf(c.w);
    s3 += fabsf(d.x) + fabsf(d.y) + fabsf(d.z) + fabsf(d.w);
  }
  float s = (s0 + s1) + (s2 + s3);
  for (int o = 32; o > 0; o >>= 1) s += __shfl_down(s, o);
  __shared__ float lds[4];
  if ((tid & 63) == 0) lds[tid >> 6] = s;
  __syncthreads();
  if (tid == 0) partials[m * 128 + blk] = lds[0] + lds[1] + lds[2] + lds[3];
}

// -------- finalize 8 scales + exact ternary compare-thresholds -------------
// thr = largest float t with fl(t/s) <= 0.5  =>  (|w|>thr) == (rint(w/s)!=0)
__global__ __launch_bounds__(128) void k_scales8(const float* __restrict__ partials,
                                                 float* __restrict__ s8,
                                                 float* __restrict__ thr8) {
  int tid = threadIdx.x;
  __shared__ float acc[2];
  __shared__ float svals[8];
  for (int m = 0; m < 8; m++) {
    float v = partials[m * 128 + tid];
    for (int o = 32; o > 0; o >>= 1) v += __shfl_down(v, o);
    if ((tid & 63) == 0) acc[tid >> 6] = v;
    __syncthreads();
    if (tid == 0) svals[m] = fmaxf((acc[0] + acc[1]) / (float)FH, EPSF);
    __syncthreads();
  }
  if (tid < 8) {
    float s = svals[tid];
    s8[tid] = s;
    unsigned int lo = 0u, hi = __float_as_uint(s);
    for (int it = 0; it < 32; ++it) {
      unsigned int mid = (lo + hi) >> 1;
      if (mid == lo) break;
      if (__uint_as_float(mid) / s <= 0.5f) lo = mid; else hi = mid;
    }
    thr8[tid] = __uint_as_float(lo);
  }
}

// ----------------- router int8 per-tensor quant (tiny) ---------------------
__global__ __launch_bounds__(256) void k_router(const float* __restrict__ wr,
                                                float* __restrict__ wrq) {
  int tid = threadIdx.x;
  __shared__ float lds[4];
  __shared__ float sbc;
  float mx = 0.f;
  for (int i = tid; i < NEXP * HDIM; i += 256) mx = fmaxf(mx, fabsf(wr[i]));
  for (int o = 32; o > 0; o >>= 1) mx = fmaxf(mx, __shfl_down(mx, o));
  if ((tid & 63) == 0) lds[tid >> 6] = mx;
  __syncthreads();
  if (tid == 0)
    sbc = fmaxf(fmaxf(fmaxf(lds[0], lds[1]), fmaxf(lds[2], lds[3])), EPSF) / 127.0f;
  __syncthreads();
  float s = sbc;
  for (int i = tid; i < NEXP * HDIM; i += 256) {
    float q = fminf(fmaxf(rintf(wr[i] / s), -127.f), 127.f);
    wrq[i] = q * s;
  }
}

// ------- pass 2: ternarize + transpose into MFMA fragment pack -------------
template <int KD, int RD>
__global__ __launch_bounds__(256) void k_pack(const float* __restrict__ w,
                                              signed char* __restrict__ q,
                                              const float* __restrict__ thr8) {
  constexpr int GR = RD / 32, CCH = KD / 32;
  int e = blockIdx.x / GR, g = blockIdx.x % GR, sl = blockIdx.y;
  float thr = thr8[e];
  __shared__ unsigned int lds[32][257];
  int tid = threadIdx.x;
  const float* wb = w + ((size_t)e * RD + (size_t)g * 32) * KD + (size_t)sl * 1024;
#pragma unroll 4
  for (int i = 0; i < 32; i++) {
    float4 v = *(const float4*)(wb + (size_t)i * KD + tid * 4);
    unsigned int b0 = (fabsf(v.x) > thr) ? ((__float_as_uint(v.x) >> 31) ? 0xFFu : 1u) : 0u;
    unsigned int b1 = (fabsf(v.y) > thr) ? ((__float_as_uint(v.y) >> 31) ? 0xFFu : 1u) : 0u;
    unsigned int b2 = (fabsf(v.z) > thr) ? ((__float_as_uint(v.z) >> 31) ? 0xFFu : 1u) : 0u;
    unsigned int b3 = (fabsf(v.w) > thr) ? ((__float_as_uint(v.w) >> 31) ? 0xFFu : 1u) : 0u;
    lds[i][tid] = b0 | (b1 << 8) | (b2 << 16) | (b3 << 24);
  }
  __syncthreads();
  size_t obase = ((size_t)(e * GR + g) * CCH + (size_t)sl * 32) * 1024;
#pragma unroll
  for (int i2 = 0; i2 < 8; i2++) {
    int mI = i2 * 256 + tid;
    int c = mI >> 6, l2 = mI & 63, ln = l2 & 31, kh = l2 >> 5;
    uint4 d = *(const uint4*)&lds[ln][c * 8 + kh * 4];
    *(uint4*)(q + obase + (size_t)c * 1024 + (size_t)l2 * 16) = d;
  }
}

// ------------- per-token int4 act quant + router + top-2 -------------------
__global__ __launch_bounds__(256) void k_act_router(const float* __restrict__ x,
                                                    const float* __restrict__ wrq,
                                                    signed char* __restrict__ xq,
                                                    float* __restrict__ sx,
                                                    int* __restrict__ tok_e,
                                                    float* __restrict__ tok_g,
                                                    int* __restrict__ cnt) {
  int t = blockIdx.x, tid = threadIdx.x;
  float4 xv = *(const float4*)(x + (size_t)t * HDIM + tid * 4);
  __shared__ float lds[4];
  __shared__ float sbc;
  __shared__ float part[8][256];
  __shared__ float lg[8];
  float mx = fmaxf(fmaxf(fabsf(xv.x), fabsf(xv.y)), fmaxf(fabsf(xv.z), fabsf(xv.w)));
  for (int o = 32; o > 0; o >>= 1) mx = fmaxf(mx, __shfl_down(mx, o));
  if ((tid & 63) == 0) lds[tid >> 6] = mx;
  __syncthreads();
  if (tid == 0)
    sbc = fmaxf(fmaxf(fmaxf(lds[0], lds[1]), fmaxf(lds[2], lds[3])), EPSF) / 7.0f;
  __syncthreads();
  float s = sbc;
  int q0 = (int)fminf(fmaxf(rintf(xv.x / s), -7.f), 7.f);
  int q1 = (int)fminf(fmaxf(rintf(xv.y / s), -7.f), 7.f);
  int q2 = (int)fminf(fmaxf(rintf(xv.z / s), -7.f), 7.f);
  int q3 = (int)fminf(fmaxf(rintf(xv.w / s), -7.f), 7.f);
  int packed = (q0 & 255) | ((q1 & 255) << 8) | ((q2 & 255) << 16) | (q3 << 24);
  *(int*)(xq + (size_t)t * HDIM + tid * 4) = packed;
  if (tid == 0) sx[t] = s;
#pragma unroll
  for (int e = 0; e < 8; e++) {
    float4 w = *(const float4*)(wrq + e * HDIM + tid * 4);
    part[e][tid] = xv.x * w.x + xv.y * w.y + xv.z * w.z + xv.w * w.w;
  }
  __syncthreads();
  if (tid < 8) {
    float sum = 0.f;
    for (int i = 0; i < 256; i++) sum += part[tid][i];
    lg[tid] = sum;
  }
  __syncthreads();
  if (tid == 0) {
    float m = lg[0];
    for (int e = 1; e < 8; e++) m = fmaxf(m, lg[e]);
    float p[8]; float S = 0.f;
    for (int e = 0; e < 8; e++) { p[e] = expf(lg[e] - m); S += p[e]; }
    for (int e = 0; e < 8; e++) p[e] /= S;
    int e0 = 0;
    for (int e = 1; e < 8; e++) if (p[e] > p[e0]) e0 = e;
    int e1 = -1;
    for (int e = 0; e < 8; e++) { if (e == e0) continue; if (e1 < 0 || p[e] > p[e1]) e1 = e; }
    float g0 = p[e0], g1 = p[e1], gs = g0 + g1;
    tok_e[2 * t] = e0;  tok_e[2 * t + 1] = e1;
    tok_g[2 * t] = g0 / gs;  tok_g[2 * t + 1] = g1 / gs;
    atomicAdd(&cnt[e0], 1); atomicAdd(&cnt[e1], 1);
  }
}

// ------------ expert offsets (128-aligned) + 128-wide tile plan ------------
__global__ void k_plan(const int* __restrict__ cnt, int* __restrict__ offs,
                       int* __restrict__ tile_e, int* __restrict__ tile_m0,
                       int* __restrict__ tile_cnt) {
  if (threadIdx.x == 0 && blockIdx.x == 0) {
    int o = 0;
    for (int e = 0; e < 8; e++) { offs[e] = o; o += (cnt[e] + 127) & ~127; }
    offs[8] = o;
    int tt = 0;
    for (int e = 0; e < 8; e++)
      for (int m0 = 0; m0 < cnt[e]; m0 += 128) { tile_e[tt] = e; tile_m0[tt] = m0; tt++; }
    *tile_cnt = tt;
  }
}

__global__ __launch_bounds__(256) void k_scatter(const int* __restrict__ tok_e,
                                                 const float* __restrict__ tok_g,
                                                 const float* __restrict__ sx,
                                                 const int* __restrict__ offs,
                                                 int* __restrict__ cnt2,
                                                 int* __restrict__ pair_tok,
                                                 float* __restrict__ pair_gate,
                                                 float* __restrict__ pair_sx) {
  int t = blockIdx.x * 256 + threadIdx.x;
  if (t >= T_TOK) return;
  for (int k = 0; k < 2; k++) {
    int e = tok_e[2 * t + k];
    int pos = offs[e] + atomicAdd(&cnt2[e], 1);
    pair_tok[pos] = t;
    pair_gate[pos] = tok_g[2 * t + k];
    pair_sx[pos] = sx[t];
  }
}

// ----------- gather xq rows into A-fragment pack (per pair) ----------------
__global__ __launch_bounds__(256) void k_packA(const int* __restrict__ pair_tok,
                                               const signed char* __restrict__ xq,
                                               signed char* __restrict__ xqp) {
  int idx = blockIdx.x * 256 + threadIdx.x;          // < PPAD*64
  int l = idx & 63, c = (idx >> 6) & 31, pgrp = idx >> 11;
  int p = pgrp * 32 + (l & 31);
  int tok = pair_tok[p];                             // pads memset to 0 -> safe
  const signed char* src = xq + (size_t)tok * HDIM + c * 32 + (l >> 5) * 16;
  *(int4*)(xqp + (size_t)idx * 16) = *(const int4*)src;
}

// -------- gate/up int8 MFMA GEMM + fused SiLU*u, writes h (fp16) -----------
// Block: 4 waves; tile M=128 (4 m-groups) x N=128 (wave-private 32 cols).
// 8 accs/wave: per K-step 6 loads feed 8 MFMAs; A loads identical across
// waves (L1 dedup) -> 87 MAC per L2 byte at block level.
__global__ __launch_bounds__(256, 2) void k_gemm_gu(const signed char* __restrict__ xqp,
                                                    const signed char* __restrict__ wgp,
                                                    const signed char* __restrict__ wup,
                                                    const int* __restrict__ tile_e,
                                                    const int* __restrict__ tile_m0,
                                                    const int* __restrict__ tile_cnt,
                                                    const int* __restrict__ cnt,
                                                    const int* __restrict__ offs,
                                                    const float* __restrict__ pair_sx,
                                                    const float* __restrict__ s_w,
                                                    unsigned short* __restrict__ hbuf) {
  int bx = blockIdx.x;
  if (bx >= *tile_cnt) return;
  int e = tile_e[bx], m0 = tile_m0[bx];
  int cnt_e = cnt[e], pbase = offs[e];
  int tid = threadIdx.x;
  int wave = tid >> 6, lane = tid & 63, ln = lane & 31, kh = lane >> 5;
  int fgrp = blockIdx.y * 4 + wave;                 // 0..127
  const signed char* bg = wgp + (((size_t)e * 128 + fgrp) * 32) * 1024 + lane * 16;
  const signed char* bu = wup + (((size_t)e * 128 + fgrp) * 32) * 1024 + lane * 16;
  const signed char* ap = xqp + ((size_t)((pbase + m0) >> 5) * 32) * 1024 + lane * 16;
  v16i acc[4][2] = {};
#pragma unroll 2
  for (int c = 0; c < 32; c++) {
    v4i a[4];
#pragma unroll
    for (int mg = 0; mg < 4; mg++)
      a[mg] = *(const v4i*)(ap + (size_t)(mg * 32 + c) * 1024);
    v4i b0 = *(const v4i*)(bg + (size_t)c * 1024);
    v4i b1 = *(const v4i*)(bu + (size_t)c * 1024);
#pragma unroll
    for (int mg = 0; mg < 4; mg++) {
      acc[mg][0] = __builtin_amdgcn_mfma_i32_32x32x32_i8(a[mg], b0, acc[mg][0], 0, 0, 0);
      acc[mg][1] = __builtin_amdgcn_mfma_i32_32x32x32_i8(a[mg], b1, acc[mg][1], 0, 0, 0);
    }
  }
  float sg = s_w[e], su = s_w[8 + e];
  int col = blockIdx.y * 128 + wave * 32 + ln;
#pragma unroll
  for (int mg = 0; mg < 4; mg++) {
#pragma unroll
    for (int r = 0; r < 16; r++) {
      int rr = (r & 3) + 8 * (r >> 2) + 4 * kh;
      int ml = m0 + mg * 32 + rr;
      if (ml < cnt_e) {
        int p = pbase + ml;
        float sxv = pair_sx[p];
        float gf = (float)acc[mg][0][r] * (sxv * sg);
        float uf = (float)acc[mg][1][r] * (sxv * su);
        float h = gf / (1.0f + expf(-gf)) * uf;
        ((_Float16*)hbuf)[(size_t)p * FDIM + col] = (_Float16)h;
      }
    }
  }
}

// ------- per-pair exact top-k via 15-step bisection on fp16 bits -----------
__global__ __launch_bounds__(256) void k_select(const unsigned short* __restrict__ hbuf,
                                                signed char* __restrict__ hqp,
                                                const float* __restrict__ pair_gate,
                                                float* __restrict__ pair_f) {
  int wv = threadIdx.x >> 6, lane = threadIdx.x & 63;
  int p = blockIdx.x * 4 + wv;
  const unsigned short* row = hbuf + (size_t)p * FDIM + lane * 64;
  unsigned short hs[64];
#pragma unroll
  for (int i = 0; i < 8; i++)
    *(uint4*)(hs + i * 8) = *(const uint4*)(row + i * 8);
  unsigned short ua[64];
  unsigned int mxb = 0;
#pragma unroll
  for (int j = 0; j < 64; j++) {
    unsigned int u = hs[j] & 0x7fffu;
    ua[j] = (unsigned short)u;
    mxb = (u > mxb) ? u : mxb;
  }
  for (int o = 32; o > 0; o >>= 1) {
    unsigned int t = (unsigned int)__shfl_down((int)mxb, o);
    mxb = (t > mxb) ? t : mxb;
  }
  mxb = (unsigned int)__shfl((int)mxb, 0);
  unsigned int lo = 0, hi = 0x7c00u;
  for (int it = 0; it < 15; ++it) {
    unsigned int mid = (lo + hi) >> 1;
    int cntk = 0;
#pragma unroll
    for (int j = 0; j < 64; j++)
      cntk += (int)__popcll(__ballot((unsigned int)ua[j] >= mid));
    if (cntk >= KTOP) lo = mid; else hi = mid;
  }
  unsigned int thr = lo;
  unsigned short mxs = (unsigned short)mxb;
  float smax = (float)(*(const _Float16*)&mxs);
  float sq = fmaxf(smax, EPSF) / 127.0f;
  int pgrp = p >> 5, ln = p & 31;
#pragma unroll
  for (int gj = 0; gj < 4; gj++) {
    int c = 2 * lane + (gj >> 1);
    int kh = gj & 1;
    signed char outb[16];
#pragma unroll
    for (int t = 0; t < 16; t++) {
      int j = gj * 16 + t;
      float v = (float)(((const _Float16*)hs)[j]);
      float m = ((unsigned int)ua[j] >= thr) ? v : 0.0f;
      float q = fminf(fmaxf(rintf(m / sq), -127.f), 127.f);
      outb[t] = (signed char)(int)q;
    }
    *(int4*)(hqp + ((size_t)((size_t)pgrp * 128 + c) * 64 + kh * 32 + ln) * 16) =
        *(const int4*)outb;
  }
  if (lane == 0) pair_f[p] = pair_gate[p] * sq;
}

// ---------- down int8 MFMA GEMM (M=128 tile, split-K=2) --------------------
__global__ __launch_bounds__(256, 2) void k_gemm_down(const signed char* __restrict__ hqp,
                                                      const signed char* __restrict__ wdp,
                                                      const int* __restrict__ tile_e,
                                                      const int* __restrict__ tile_m0,
                                                      const int* __restrict__ tile_cnt,
                                                      const int* __restrict__ cnt,
                                                      const int* __restrict__ offs,
                                                      const int* __restrict__ pair_tok,
                                                      const float* __restrict__ pair_f,
                                                      const float* __restrict__ s_w,
                                                      float* __restrict__ out) {
  int bx = blockIdx.x;
  if (bx >= *tile_cnt) return;
  int e = tile_e[bx], m0 = tile_m0[bx];
  int cnt_e = cnt[e], pbase = offs[e];
  int tid = threadIdx.x;
  int wave = tid >> 6, lane = tid & 63, ln = lane & 31, kh = lane >> 5;
  int ggrp = blockIdx.y * 4 + wave;                 // 0..31 over HDIM rows of wd
  int c0 = blockIdx.z * 64;                         // split-K half
  const signed char* bp = wdp + (((size_t)e * 32 + ggrp) * 128) * 1024 + lane * 16;
  const signed char* ap = hqp + ((size_t)((pbase + m0) >> 5) * 128) * 1024 + lane * 16;
  v16i acc[4] = {};
#pragma unroll 4
  for (int c = c0; c < c0 + 64; c++) {
    v4i a[4];
#pragma unroll
    for (int mg = 0; mg < 4; mg++)
      a[mg] = *(const v4i*)(ap + (size_t)(mg * 128 + c) * 1024);
    v4i b = *(const v4i*)(bp + (size_t)c * 1024);
#pragma unroll
    for (int mg = 0; mg < 4; mg++)
      acc[mg] = __builtin_amdgcn_mfma_i32_32x32x32_i8(a[mg], b, acc[mg], 0, 0, 0);
  }
  float sd = s_w[16 + e];
  int col = blockIdx.y * 128 + wave * 32 + ln;
#pragma unroll
  for (int mg = 0; mg < 4; mg++) {
#pragma unroll
    for (int r = 0; r < 16; r++) {
      int rr = (r & 3) + 8 * (r >> 2) + 4 * kh;
      int ml = m0 + mg * 32 + rr;
      if (ml < cnt_e) {
        int p = pbase + ml;
        float v = (float)acc[mg][r] * (pair_f[p] * sd);
        atomicAdd(out + (size_t)pair_tok[p] * HDIM + col, v);
      }
    }
  }
}

// ---------------------------------------------------------------------------
extern "C" void kernel_launch(void* const* d_in, const int* in_sizes, int n_in,
                              void* d_out, int out_size, void* d_ws, size_t ws_size,
                              hipStream_t stream) {
  const float* x  = (const float*)d_in[0];
  const float* wg = (const float*)d_in[1];
  const float* wu = (const float*)d_in[2];
  const float* wd = (const float*)d_in[3];
  const float* wr = (const float*)d_in[4];
  float* out = (float*)d_out;
  char* ws = (char*)d_ws;
  (void)in_sizes; (void)n_in; (void)out_size; (void)ws_size;

  size_t o = 0;
  auto alloc = [&](size_t b) { size_t r = o; o += (b + 255) & ~(size_t)255; return r; };
  float* partials   = (float*)(ws + alloc(3 * 8 * 128 * 4));
  float* s_w        = (float*)(ws + alloc(24 * 4));
  float* thr_w      = (float*)(ws + alloc(24 * 4));
  float* wrq        = (float*)(ws + alloc((size_t)NEXP * HDIM * 4));
  int*   tok_e      = (int*)  (ws + alloc((size_t)T_TOK * 2 * 4));
  float* tok_g      = (float*)(ws + alloc((size_t)T_TOK * 2 * 4));
  int*   cnt        = (int*)  (ws + alloc(256));      // cnt[8] then cnt2[8]
  int*   cnt2       = cnt + 8;
  int*   offs       = (int*)  (ws + alloc(16 * 4));
  int*   tile_e     = (int*)  (ws + alloc(128 * 4));
  int*   tile_m0    = (int*)  (ws + alloc(128 * 4));
  int*   tile_cnt   = (int*)  (ws + alloc(4));
  int*   pair_tok   = (int*)  (ws + alloc((size_t)PPAD * 4));
  float* pair_gate  = (float*)(ws + alloc((size_t)PPAD * 4));
  float* pair_sx    = (float*)(ws + alloc((size_t)PPAD * 4));
  float* pair_f     = (float*)(ws + alloc((size_t)PPAD * 4));
  float* sx         = (float*)(ws + alloc((size_t)T_TOK * 4));
  signed char* xq   = (signed char*)(ws + alloc((size_t)T_TOK * HDIM));
  signed char* xqp  = (signed char*)(ws + alloc((size_t)PPAD * HDIM));
  signed char* wgp  = (signed char*)(ws + alloc((size_t)NEXP * FH));
  signed char* wup  = (signed char*)(ws + alloc((size_t)NEXP * FH));
  signed char* wdp  = (signed char*)(ws + alloc((size_t)NEXP * FH));
  unsigned short* hbuf = (unsigned short*)(ws + alloc((size_t)PPAD * FDIM * 2));
  signed char* hqp  = (signed char*)(ws + alloc((size_t)PPAD * FDIM));

  hipMemsetAsync(cnt, 0, 64, stream);
  hipMemsetAsync(pair_tok, 0, (size_t)PPAD * 4, stream);
  hipMemsetAsync(out, 0, (size_t)T_TOK * HDIM * 4, stream);

  // per-tensor: wabs -> scales -> pack (tensor stays L3-resident for pack)
  k_wabs<<<dim3(8, 128), 256, 0, stream>>>(wg, partials);
  k_scales8<<<1, 128, 0, stream>>>(partials, s_w, thr_w);
  k_pack<1024, 4096><<<dim3(1024, 1), 256, 0, stream>>>(wg, wgp, thr_w);

  k_wabs<<<dim3(8, 128), 256, 0, stream>>>(wu, partials + 1024);
  k_scales8<<<1, 128, 0, stream>>>(partials + 1024, s_w + 8, thr_w + 8);
  k_pack<1024, 4096><<<dim3(1024, 1), 256, 0, stream>>>(wu, wup, thr_w + 8);

  k_wabs<<<dim3(8, 128), 256, 0, stream>>>(wd, partials + 2048);
  k_scales8<<<1, 128, 0, stream>>>(partials + 2048, s_w + 16, thr_w + 16);
  k_pack<4096, 1024><<<dim3(256, 4), 256, 0, stream>>>(wd, wdp, thr_w + 16);

  k_router<<<1, 256, 0, stream>>>(wr, wrq);
  k_act_router<<<T_TOK, 256, 0, stream>>>(x, wrq, xq, sx, tok_e, tok_g, cnt);
  k_plan<<<1, 64, 0, stream>>>(cnt, offs, tile_e, tile_m0, tile_cnt);
  k_scatter<<<8, 256, 0, stream>>>(tok_e, tok_g, sx, offs, cnt2, pair_tok, pair_gate, pair_sx);
  k_packA<<<PPAD / 4, 256, 0, stream>>>(pair_tok, xq, xqp);
  k_gemm_gu<<<dim3(40, 32), 256, 0, stream>>>(xqp, wgp, wup, tile_e, tile_m0, tile_cnt,
                                              cnt, offs, pair_sx, s_w, hbuf);
  k_select<<<PPAD / 4, 256, 0, stream>>>(hbuf, hqp, pair_gate, pair_f);
  k_gemm_down<<<dim3(40, 8, 2), 256, 0, stream>>>(hqp, wdp, tile_e, tile_m0, tile_cnt,
                                                  cnt, offs, pair_tok, pair_f, s_w, out);
}